// Round 5
// baseline (155409.814 us; speedup 1.0000x reference)
//
#include <hip/hip_runtime.h>
#include <stdint.h>

#define MDIM   1024
#define NGATE5 5120
#define TSTEPS 8192
#define NWG    256
#define NTHR   256

__device__ __forceinline__ float sigmoidf_(float x) {
  return 1.f / (1.f + __expf(-x));
}

// Poll this thread's 4 tagged u64 slots until all tags==want, staging the
// fp32 payloads into LDS dst. R5: per-round agent acquire fence (buffer_inv,
// invalidates L1+L2) + CACHEABLE loads, so the 32 WGs of an XCD share L2
// fills of the slot region instead of each issuing sc0sc1 fabric reads
// (R4 post-mortem: ~2 MB of LLC-bypass traffic per poll round was the
// dominant per-exchange cost). Tag+value share one 8-B atom -> no ordering.
__device__ __forceinline__ void poll_stage(const unsigned long long* __restrict__ slots,
                                           float* __restrict__ dst, int base, unsigned want) {
  unsigned long long e0, e1, e2, e3;
  for (;;) {
    __builtin_amdgcn_fence(__ATOMIC_ACQUIRE, "agent");
    e0 = __hip_atomic_load(slots + base + 0, __ATOMIC_RELAXED, __HIP_MEMORY_SCOPE_WORKGROUP);
    e1 = __hip_atomic_load(slots + base + 1, __ATOMIC_RELAXED, __HIP_MEMORY_SCOPE_WORKGROUP);
    e2 = __hip_atomic_load(slots + base + 2, __ATOMIC_RELAXED, __HIP_MEMORY_SCOPE_WORKGROUP);
    e3 = __hip_atomic_load(slots + base + 3, __ATOMIC_RELAXED, __HIP_MEMORY_SCOPE_WORKGROUP);
    if ((unsigned)(e0 >> 32) == want && (unsigned)(e1 >> 32) == want &&
        (unsigned)(e2 >> 32) == want && (unsigned)(e3 >> 32) == want) break;
  }
  dst[base + 0] = __uint_as_float((unsigned)e0);
  dst[base + 1] = __uint_as_float((unsigned)e1);
  dst[base + 2] = __uint_as_float((unsigned)e2);
  dst[base + 3] = __uint_as_float((unsigned)e3);
}

__device__ __forceinline__ unsigned long long pack_slot(float v, unsigned tag) {
  return ((unsigned long long)tag << 32) | (unsigned long long)__float_as_uint(v);
}

// ---------------------------------------------------------------------------
// Prepass: xproj[t][r] = inputs[t,:]@Wx[r,:] + bx[r] + (r<4M ? bh[r] : bm[r-4M])
// ---------------------------------------------------------------------------
#define GT_K 16
__global__ __launch_bounds__(256) void xproj_gemm(
    const float* __restrict__ A, const float* __restrict__ W,
    const float* __restrict__ bx, const float* __restrict__ bh,
    const float* __restrict__ bm, float* __restrict__ C)
{
  __shared__ float As[GT_K][64 + 4];
  __shared__ float Ws[GT_K][64 + 4];
  const int tid = threadIdx.x;
  const int tx = tid & 15, ty = tid >> 4;
  const int m0 = blockIdx.x * 64;
  const int n0 = blockIdx.y * 64;
  const int lr = tid >> 2;
  const int lk = (tid & 3) * 4;

  float acc[4][4] = {};
  for (int kb = 0; kb < MDIM; kb += GT_K) {
    const float4 av = *(const float4*)(A + (size_t)(m0 + lr) * MDIM + kb + lk);
    const float4 wv = *(const float4*)(W + (size_t)(n0 + lr) * MDIM + kb + lk);
    __syncthreads();
    As[lk + 0][lr] = av.x; As[lk + 1][lr] = av.y;
    As[lk + 2][lr] = av.z; As[lk + 3][lr] = av.w;
    Ws[lk + 0][lr] = wv.x; Ws[lk + 1][lr] = wv.y;
    Ws[lk + 2][lr] = wv.z; Ws[lk + 3][lr] = wv.w;
    __syncthreads();
    #pragma unroll
    for (int kk = 0; kk < GT_K; ++kk) {
      const float4 a = *(const float4*)(&As[kk][ty * 4]);
      const float4 w = *(const float4*)(&Ws[kk][tx * 4]);
      acc[0][0] += a.x * w.x; acc[0][1] += a.x * w.y; acc[0][2] += a.x * w.z; acc[0][3] += a.x * w.w;
      acc[1][0] += a.y * w.x; acc[1][1] += a.y * w.y; acc[1][2] += a.y * w.z; acc[1][3] += a.y * w.w;
      acc[2][0] += a.z * w.x; acc[2][1] += a.z * w.y; acc[2][2] += a.z * w.z; acc[2][3] += a.z * w.w;
      acc[3][0] += a.w * w.x; acc[3][1] += a.w * w.y; acc[3][2] += a.w * w.z; acc[3][3] += a.w * w.w;
    }
  }
  const int rbase = n0 + tx * 4;
  float bias[4];
  #pragma unroll
  for (int q = 0; q < 4; ++q) {
    const int r = rbase + q;
    bias[q] = bx[r] + (r < 4 * MDIM ? bh[r] : bm[r - 4 * MDIM]);
  }
  #pragma unroll
  for (int i = 0; i < 4; ++i) {
    const int row = m0 + ty * 4 + i;
    float4 o;
    o.x = acc[i][0] + bias[0]; o.y = acc[i][1] + bias[1];
    o.z = acc[i][2] + bias[2]; o.w = acc[i][3] + bias[3];
    *(float4*)(C + (size_t)row * NGATE5 + rbase) = o;
  }
}

// ---------------------------------------------------------------------------
// Recurrence. Wave owns column j. Weights fp32 in LDS. Critical path:
// h arrives -> z-dot -> publish v -> (i,o,f dots overlap v-wait) ->
// v arrives -> u-dot -> c,h -> publish h.
// ---------------------------------------------------------------------------
__global__ __launch_bounds__(NTHR, 1) void ulstm_persistent_p(
    const float* __restrict__ Wh, const float* __restrict__ Wm,
    const float* __restrict__ xproj, float* __restrict__ out,
    unsigned long long* __restrict__ hslot, unsigned long long* __restrict__ vslot)
{
  __shared__ alignas(16) float sWh[16][MDIM];   // [wave*4+gate][k]  64 KB
  __shared__ alignas(16) float sWm[4][MDIM];    // [wave][k]         16 KB
  __shared__ alignas(16) float hbuf[MDIM];
  __shared__ alignas(16) float vbuf[MDIM];

  const int tid  = threadIdx.x;
  const int wg   = blockIdx.x;
  const int wave = tid >> 6;
  const int lane = tid & 63;
  const int j    = wg * 4 + wave;
  const int slotbase = tid * 4;

  // ---- one-time weight staging into LDS (fp32, float4) ----
  for (int idx = tid; idx < 16 * 256; idx += NTHR) {
    const int r = idx >> 8, k4 = (idx & 255) * 4;
    const int w_ = r >> 2, g = r & 3;
    *(float4*)(&sWh[r][k4]) =
        *(const float4*)(Wh + (size_t)(g * MDIM + wg * 4 + w_) * MDIM + k4);
  }
  for (int idx = tid; idx < 4 * 256; idx += NTHR) {
    const int r = idx >> 8, k4 = (idx & 255) * 4;
    *(float4*)(&sWm[r][k4]) =
        *(const float4*)(Wm + (size_t)(wg * 4 + r) * MDIM + k4);
  }
  __syncthreads();

  float c = 0.f, hlast = 0.f, tc = 0.f;   // tc = tanh(c), maintained off-path

  for (int t = 0; t < TSTEPS; ++t) {
    // xproj for this step (wave-uniform, cacheable stream; drains at first fence)
    const float* xp = xproj + (size_t)t * NGATE5 + j;
    const float xw0 = xp[0 * MDIM];
    const float xw1 = xp[1 * MDIM];
    const float xw2 = xp[2 * MDIM];
    const float xw3 = xp[3 * MDIM];
    const float xw4 = xp[4 * MDIM];

    // ---- wait for h(t-1): tag==t ----
    poll_stage(hslot, hbuf, slotbase, (unsigned)t);
    __syncthreads();  // S2

    // ---- z-dot only (critical path), then publish v ----
    float hd2 = 0.f;
    #pragma unroll
    for (int i = 0; i < 4; ++i) {
      const float4 hv = *(const float4*)(hbuf + i * 256 + lane * 4);
      const float4 w2 = *(const float4*)(&sWh[wave * 4 + 2][i * 256 + lane * 4]);
      hd2 += w2.x * hv.x + w2.y * hv.y + w2.z * hv.z + w2.w * hv.w;
    }
    #pragma unroll
    for (int off = 32; off > 0; off >>= 1) hd2 += __shfl_xor(hd2, off, 64);

    const float zg = sigmoidf_(xw2 + hd2);
    const float vj = zg * tc;
    if (lane == 0) {
      __hip_atomic_store(vslot + j, pack_slot(vj, (unsigned)(t + 1)),
                         __ATOMIC_RELAXED, __HIP_MEMORY_SCOPE_AGENT);
    }

    // ---- i,o,f dots: overlap with the v-exchange ----
    float hd0 = 0.f, hd1 = 0.f, hd3 = 0.f;
    #pragma unroll
    for (int i = 0; i < 4; ++i) {
      const int kb = i * 256 + lane * 4;
      const float4 hv = *(const float4*)(hbuf + kb);
      const float4 w0 = *(const float4*)(&sWh[wave * 4 + 0][kb]);
      const float4 w1 = *(const float4*)(&sWh[wave * 4 + 1][kb]);
      const float4 w3 = *(const float4*)(&sWh[wave * 4 + 3][kb]);
      hd0 += w0.x * hv.x + w0.y * hv.y + w0.z * hv.z + w0.w * hv.w;
      hd1 += w1.x * hv.x + w1.y * hv.y + w1.z * hv.z + w1.w * hv.w;
      hd3 += w3.x * hv.x + w3.y * hv.y + w3.z * hv.z + w3.w * hv.w;
    }
    #pragma unroll
    for (int off = 32; off > 0; off >>= 1) {
      hd0 += __shfl_xor(hd0, off, 64);
      hd1 += __shfl_xor(hd1, off, 64);
      hd3 += __shfl_xor(hd3, off, 64);
    }
    const float ig = sigmoidf_(xw0 + hd0);
    const float og = sigmoidf_(xw1 + hd1);
    const float fg = sigmoidf_(xw3 + hd3);

    // ---- wait for v(t): tag==t+1 ----
    poll_stage(vslot, vbuf, slotbase, (unsigned)(t + 1));
    __syncthreads();  // S3

    // ---- u-dot ----
    float md = 0.f;
    #pragma unroll
    for (int i = 0; i < 4; ++i) {
      const int kb = i * 256 + lane * 4;
      const float4 vv = *(const float4*)(vbuf + kb);
      const float4 wv = *(const float4*)(&sWm[wave][kb]);
      md += wv.x * vv.x + wv.y * vv.y + wv.z * vv.z + wv.w * vv.w;
    }
    #pragma unroll
    for (int off = 32; off > 0; off >>= 1) md += __shfl_xor(md, off, 64);

    const float u = tanhf(xw4 + md);
    c = ig * u + fg * c;
    const float tcn = tanhf(c);
    hlast = og * tcn;
    if (lane == 0) {
      __hip_atomic_store(hslot + j, pack_slot(hlast, (unsigned)(t + 1)),
                         __ATOMIC_RELAXED, __HIP_MEMORY_SCOPE_AGENT);
    }
    tc = tcn;
  }

  if (lane == 0) {
    out[j] = c;
    out[MDIM + j] = hlast;
  }
}

// ---------------------------------------------------------------------------
// Fallback (ws too small for xproj): R2 structure, weights re-read from cache.
// ---------------------------------------------------------------------------
__global__ __launch_bounds__(NTHR, 1) void ulstm_persistent_f(
    const float* __restrict__ inputs, const float* __restrict__ Wx,
    const float* __restrict__ bx, const float* __restrict__ Wh,
    const float* __restrict__ bh, const float* __restrict__ Wm,
    const float* __restrict__ bm, float* __restrict__ out,
    unsigned long long* __restrict__ hslot, unsigned long long* __restrict__ vslot)
{
  __shared__ alignas(16) float xbuf[MDIM];
  __shared__ alignas(16) float hbuf[MDIM];
  __shared__ alignas(16) float vbuf[MDIM];

  const int tid  = threadIdx.x;
  const int wg   = blockIdx.x;
  const int wave = tid >> 6;
  const int lane = tid & 63;
  const int j    = wg * 4 + wave;
  const int slotbase = tid * 4;

  const float bxi = bx[j],            bxo = bx[MDIM + j],
              bxz = bx[2 * MDIM + j], bxf = bx[3 * MDIM + j],
              bxu = bx[4 * MDIM + j];
  const float bhi = bh[j],            bho = bh[MDIM + j],
              bhz = bh[2 * MDIM + j], bhf = bh[3 * MDIM + j];
  const float bmj = bm[j];

  float c = 0.f, hlast = 0.f;

  for (int t = 0; t < TSTEPS; ++t) {
    {
      float4 v = ((const float4*)(inputs + (size_t)t * MDIM))[tid];
      ((float4*)xbuf)[tid] = v;
    }
    __syncthreads();

    float xd[5] = {0, 0, 0, 0, 0};
    #pragma unroll
    for (int i = 0; i < 4; ++i) {
      const int kb = i * 256 + lane * 4;
      const float4 xv = *(const float4*)(xbuf + kb);
      #pragma unroll
      for (int g = 0; g < 5; ++g) {
        const float4 w = *(const float4*)(Wx + ((size_t)(g * MDIM + j)) * MDIM + kb);
        xd[g] += w.x * xv.x + w.y * xv.y + w.z * xv.z + w.w * xv.w;
      }
    }
    #pragma unroll
    for (int off = 32; off > 0; off >>= 1)
      #pragma unroll
      for (int g = 0; g < 5; ++g) xd[g] += __shfl_xor(xd[g], off, 64);

    poll_stage(hslot, hbuf, slotbase, (unsigned)t);
    __syncthreads();

    float hd[4] = {0, 0, 0, 0};
    #pragma unroll
    for (int i = 0; i < 4; ++i) {
      const int kb = i * 256 + lane * 4;
      const float4 hv = *(const float4*)(hbuf + kb);
      #pragma unroll
      for (int g = 0; g < 4; ++g) {
        const float4 w = *(const float4*)(Wh + ((size_t)(g * MDIM + j)) * MDIM + kb);
        hd[g] += w.x * hv.x + w.y * hv.y + w.z * hv.z + w.w * hv.w;
      }
    }
    #pragma unroll
    for (int off = 32; off > 0; off >>= 1)
      #pragma unroll
      for (int g = 0; g < 4; ++g) hd[g] += __shfl_xor(hd[g], off, 64);

    const float ig = sigmoidf_(xd[0] + bxi + hd[0] + bhi);
    const float og = sigmoidf_(xd[1] + bxo + hd[1] + bho);
    const float zg = sigmoidf_(xd[2] + bxz + hd[2] + bhz);
    const float fg = sigmoidf_(xd[3] + bxf + hd[3] + bhf);
    const float vj = zg * tanhf(c);
    if (lane == 0)
      __hip_atomic_store(vslot + j, pack_slot(vj, (unsigned)(t + 1)),
                         __ATOMIC_RELAXED, __HIP_MEMORY_SCOPE_AGENT);

    poll_stage(vslot, vbuf, slotbase, (unsigned)(t + 1));
    __syncthreads();

    float md = 0;
    #pragma unroll
    for (int i = 0; i < 4; ++i) {
      const int kb = i * 256 + lane * 4;
      const float4 vv = *(const float4*)(vbuf + kb);
      const float4 w = *(const float4*)(Wm + (size_t)j * MDIM + kb);
      md += w.x * vv.x + w.y * vv.y + w.z * vv.z + w.w * vv.w;
    }
    #pragma unroll
    for (int off = 32; off > 0; off >>= 1) md += __shfl_xor(md, off, 64);

    const float u = tanhf(xd[4] + bxu + md + bmj);
    c = ig * u + fg * c;
    hlast = og * tanhf(c);
    if (lane == 0)
      __hip_atomic_store(hslot + j, pack_slot(hlast, (unsigned)(t + 1)),
                         __ATOMIC_RELAXED, __HIP_MEMORY_SCOPE_AGENT);
  }

  if (lane == 0) {
    out[j] = c;
    out[MDIM + j] = hlast;
  }
}

extern "C" void kernel_launch(void* const* d_in, const int* in_sizes, int n_in,
                              void* d_out, int out_size, void* d_ws, size_t ws_size,
                              hipStream_t stream) {
  const float* inputs = (const float*)d_in[0];
  const float* Wx     = (const float*)d_in[1];
  const float* bx     = (const float*)d_in[2];
  const float* Wh     = (const float*)d_in[3];
  const float* bh     = (const float*)d_in[4];
  const float* Wm     = (const float*)d_in[5];
  const float* bm     = (const float*)d_in[6];
  float* out = (float*)d_out;

  unsigned long long* hslot = (unsigned long long*)d_ws;
  unsigned long long* vslot = hslot + MDIM;
  const size_t slot_bytes = 2 * MDIM * sizeof(unsigned long long);
  const size_t xp_bytes   = (size_t)TSTEPS * NGATE5 * sizeof(float);

  hipMemsetAsync(d_ws, 0, slot_bytes, stream);

  if (ws_size >= slot_bytes + xp_bytes) {
    float* xproj = (float*)((char*)d_ws + slot_bytes);
    xproj_gemm<<<dim3(TSTEPS / 64, NGATE5 / 64), 256, 0, stream>>>(
        inputs, Wx, bx, bh, bm, xproj);
    ulstm_persistent_p<<<NWG, NTHR, 0, stream>>>(Wh, Wm, xproj, out, hslot, vslot);
  } else {
    ulstm_persistent_f<<<NWG, NTHR, 0, stream>>>(inputs, Wx, bx, Wh, bh, Wm, bm,
                                                 out, hslot, vslot);
  }
}

// Round 6
// 35313.309 us; speedup vs baseline: 4.4009x; 4.4009x over previous
//
#include <hip/hip_runtime.h>
#include <stdint.h>

#define MDIM   1024
#define NGATE5 5120
#define TSTEPS 8192
#define NWG    128
#define NTHR   512

typedef unsigned int u32x4 __attribute__((ext_vector_type(4)));

__device__ __forceinline__ float sigmoidf_(float x) {
  return 1.f / (1.f + __expf(-x));
}
// Fast tanh: avoids OCML tanhf (~50+ inst) on the critical path. ~1e-6 abs err.
__device__ __forceinline__ float tanhf_(float x) {
  float ax = fminf(fabsf(x), 15.f);
  float e = __expf(2.f * ax);
  float t = 1.f - 2.f / (e + 1.f);
  return copysignf(t, x);
}

// One 16-B LLC-coherent load (bypasses L1/L2: per-XCD L2s are not coherent).
// Single load + single waitcnt = one fabric round trip per poll round.
// (R5 post-mortem: per-round agent acquire fence (buffer_inv) + cacheable
// loads was 3.8x WORSE - invalidate storms serialize at L2. Bypass loads are
// the right primitive. R4 post-mortem: two serialized vmcnt(0) loads per
// round doubled round latency - fixed by 2 slots/thread.)
__device__ __forceinline__ u32x4 load16_coherent(const unsigned long long* p) {
  u32x4 r;
  asm volatile("global_load_dwordx4 %0, %1, off sc0 sc1\n\t"
               "s_waitcnt vmcnt(0)"
               : "=&v"(r) : "v"(p) : "memory");
  return r;
}

__device__ __forceinline__ unsigned long long pack_slot(float v, unsigned tag) {
  return ((unsigned long long)tag << 32) | (unsigned long long)__float_as_uint(v);
}

// ---------------------------------------------------------------------------
// Prepass: xproj[t][r] = inputs[t,:]@Wx[r,:] + bx[r] + (r<4M ? bh[r] : bm[r-4M])
// ---------------------------------------------------------------------------
#define GT_K 16
__global__ __launch_bounds__(256) void xproj_gemm(
    const float* __restrict__ A, const float* __restrict__ W,
    const float* __restrict__ bx, const float* __restrict__ bh,
    const float* __restrict__ bm, float* __restrict__ C)
{
  __shared__ float As[GT_K][64 + 4];
  __shared__ float Ws[GT_K][64 + 4];
  const int tid = threadIdx.x;
  const int tx = tid & 15, ty = tid >> 4;
  const int m0 = blockIdx.x * 64;
  const int n0 = blockIdx.y * 64;
  const int lr = tid >> 2;
  const int lk = (tid & 3) * 4;

  float acc[4][4] = {};
  for (int kb = 0; kb < MDIM; kb += GT_K) {
    const float4 av = *(const float4*)(A + (size_t)(m0 + lr) * MDIM + kb + lk);
    const float4 wv = *(const float4*)(W + (size_t)(n0 + lr) * MDIM + kb + lk);
    __syncthreads();
    As[lk + 0][lr] = av.x; As[lk + 1][lr] = av.y;
    As[lk + 2][lr] = av.z; As[lk + 3][lr] = av.w;
    Ws[lk + 0][lr] = wv.x; Ws[lk + 1][lr] = wv.y;
    Ws[lk + 2][lr] = wv.z; Ws[lk + 3][lr] = wv.w;
    __syncthreads();
    #pragma unroll
    for (int kk = 0; kk < GT_K; ++kk) {
      const float4 a = *(const float4*)(&As[kk][ty * 4]);
      const float4 w = *(const float4*)(&Ws[kk][tx * 4]);
      acc[0][0] += a.x * w.x; acc[0][1] += a.x * w.y; acc[0][2] += a.x * w.z; acc[0][3] += a.x * w.w;
      acc[1][0] += a.y * w.x; acc[1][1] += a.y * w.y; acc[1][2] += a.y * w.z; acc[1][3] += a.y * w.w;
      acc[2][0] += a.z * w.x; acc[2][1] += a.z * w.y; acc[2][2] += a.z * w.z; acc[2][3] += a.z * w.w;
      acc[3][0] += a.w * w.x; acc[3][1] += a.w * w.y; acc[3][2] += a.w * w.z; acc[3][3] += a.w * w.w;
    }
  }
  const int rbase = n0 + tx * 4;
  float bias[4];
  #pragma unroll
  for (int q = 0; q < 4; ++q) {
    const int r = rbase + q;
    bias[q] = bx[r] + (r < 4 * MDIM ? bh[r] : bm[r - 4 * MDIM]);
  }
  #pragma unroll
  for (int i = 0; i < 4; ++i) {
    const int row = m0 + ty * 4 + i;
    float4 o;
    o.x = acc[i][0] + bias[0]; o.y = acc[i][1] + bias[1];
    o.z = acc[i][2] + bias[2]; o.w = acc[i][3] + bias[3];
    *(float4*)(C + (size_t)row * NGATE5 + rbase) = o;
  }
}

// ---------------------------------------------------------------------------
// Recurrence: 128 WGs x 512 threads (8 waves). Wave w owns column j=wg*8+w.
// Wh fp32 in LDS (128 KB), Wm in 16 VGPRs/lane, h/v bufs 8 KB -> 136 KB LDS.
// Each thread polls 2 slots (one dwordx4 = one fabric trip per round);
// device-wide poll traffic 1 MB/round (half of R4).
// Critical path: h arrives -> z-dot -> publish v -> (i,o,f dots overlap
// v-wait) -> v arrives -> u-dot -> c,h -> publish h.
// ---------------------------------------------------------------------------
__global__ __launch_bounds__(NTHR, 2) void ulstm_persistent_p(
    const float* __restrict__ Wh, const float* __restrict__ Wm,
    const float* __restrict__ xproj, float* __restrict__ out,
    unsigned long long* __restrict__ hslot, unsigned long long* __restrict__ vslot)
{
  __shared__ alignas(16) float sWh[32][MDIM];   // [wave*4+gate][k]  128 KB
  __shared__ alignas(16) float hbuf[MDIM];
  __shared__ alignas(16) float vbuf[MDIM];

  const int tid  = threadIdx.x;
  const int wg   = blockIdx.x;
  const int wave = tid >> 6;
  const int lane = tid & 63;
  const int j    = wg * 8 + wave;          // owned column, 0..1023
  const int sb   = tid * 2;                // 2 slots per thread

  // ---- one-time weight staging: Wh -> LDS (fp32, float4) ----
  for (int idx = tid; idx < 32 * 256; idx += NTHR) {
    const int r = idx >> 8, k4 = (idx & 255) * 4;
    const int w_ = r >> 2, g = r & 3;
    *(float4*)(&sWh[r][k4]) =
        *(const float4*)(Wh + (size_t)(g * MDIM + wg * 8 + w_) * MDIM + k4);
  }
  // ---- Wm row for owned column -> registers (16 floats/lane) ----
  float wm[16];
  #pragma unroll
  for (int i = 0; i < 4; ++i) {
    const float4 v = *(const float4*)(Wm + (size_t)j * MDIM + i * 256 + lane * 4);
    wm[i * 4 + 0] = v.x; wm[i * 4 + 1] = v.y;
    wm[i * 4 + 2] = v.z; wm[i * 4 + 3] = v.w;
  }
  __syncthreads();

  float c = 0.f, hlast = 0.f, tc = 0.f;   // tc = tanh(c), maintained off-path

  for (int t = 0; t < TSTEPS; ++t) {
    // xproj for this step (issued before the poll; first poll round drains it)
    const float* xp = xproj + (size_t)t * NGATE5 + j;
    const float xw0 = xp[0 * MDIM];
    const float xw1 = xp[1 * MDIM];
    const float xw2 = xp[2 * MDIM];
    const float xw3 = xp[3 * MDIM];
    const float xw4 = xp[4 * MDIM];

    // ---- wait for h(t-1): tag==t (memset gives tag0/val0 = h(-1)=0) ----
    {
      u32x4 a;
      for (;;) {
        a = load16_coherent(hslot + sb);
        if (a.y == (unsigned)t && a.w == (unsigned)t) break;
      }
      hbuf[sb + 0] = __uint_as_float(a.x);
      hbuf[sb + 1] = __uint_as_float(a.z);
    }
    __syncthreads();  // S2

    // ---- z-dot only (critical path), then publish v ----
    float hd2 = 0.f;
    #pragma unroll
    for (int i = 0; i < 4; ++i) {
      const int kb = i * 256 + lane * 4;
      const float4 hv = *(const float4*)(hbuf + kb);
      const float4 w2 = *(const float4*)(&sWh[wave * 4 + 2][kb]);
      hd2 += w2.x * hv.x + w2.y * hv.y + w2.z * hv.z + w2.w * hv.w;
    }
    #pragma unroll
    for (int off = 32; off > 0; off >>= 1) hd2 += __shfl_xor(hd2, off, 64);

    const float zg = sigmoidf_(xw2 + hd2);
    const float vj = zg * tc;
    if (lane == 0) {
      __hip_atomic_store(vslot + j, pack_slot(vj, (unsigned)(t + 1)),
                         __ATOMIC_RELAXED, __HIP_MEMORY_SCOPE_AGENT);
    }

    // ---- i,o,f dots: overlap with the v-exchange ----
    float hd0 = 0.f, hd1 = 0.f, hd3 = 0.f;
    #pragma unroll
    for (int i = 0; i < 4; ++i) {
      const int kb = i * 256 + lane * 4;
      const float4 hv = *(const float4*)(hbuf + kb);
      const float4 w0 = *(const float4*)(&sWh[wave * 4 + 0][kb]);
      const float4 w1 = *(const float4*)(&sWh[wave * 4 + 1][kb]);
      const float4 w3 = *(const float4*)(&sWh[wave * 4 + 3][kb]);
      hd0 += w0.x * hv.x + w0.y * hv.y + w0.z * hv.z + w0.w * hv.w;
      hd1 += w1.x * hv.x + w1.y * hv.y + w1.z * hv.z + w1.w * hv.w;
      hd3 += w3.x * hv.x + w3.y * hv.y + w3.z * hv.z + w3.w * hv.w;
    }
    #pragma unroll
    for (int off = 32; off > 0; off >>= 1) {
      hd0 += __shfl_xor(hd0, off, 64);
      hd1 += __shfl_xor(hd1, off, 64);
      hd3 += __shfl_xor(hd3, off, 64);
    }
    const float ig = sigmoidf_(xw0 + hd0);
    const float og = sigmoidf_(xw1 + hd1);
    const float fg = sigmoidf_(xw3 + hd3);

    // ---- wait for v(t): tag==t+1 ----
    {
      u32x4 a;
      for (;;) {
        a = load16_coherent(vslot + sb);
        if (a.y == (unsigned)(t + 1) && a.w == (unsigned)(t + 1)) break;
      }
      vbuf[sb + 0] = __uint_as_float(a.x);
      vbuf[sb + 1] = __uint_as_float(a.z);
    }
    __syncthreads();  // S3

    // ---- u-dot from registers ----
    float md = 0.f;
    #pragma unroll
    for (int i = 0; i < 4; ++i) {
      const int kb = i * 256 + lane * 4;
      const float4 vv = *(const float4*)(vbuf + kb);
      md += wm[i*4+0]*vv.x + wm[i*4+1]*vv.y + wm[i*4+2]*vv.z + wm[i*4+3]*vv.w;
    }
    #pragma unroll
    for (int off = 32; off > 0; off >>= 1) md += __shfl_xor(md, off, 64);

    const float u = tanhf_(xw4 + md);
    c = ig * u + fg * c;
    const float tcn = tanhf_(c);
    hlast = og * tcn;
    if (lane == 0) {
      __hip_atomic_store(hslot + j, pack_slot(hlast, (unsigned)(t + 1)),
                         __ATOMIC_RELAXED, __HIP_MEMORY_SCOPE_AGENT);
    }
    tc = tcn;
  }

  if (lane == 0) {
    out[j] = c;
    out[MDIM + j] = hlast;
  }
}

// ---------------------------------------------------------------------------
// Fallback (ws too small for xproj): 256 WGs x 256 thr, weights from cache,
// 4 slots/thread fused-wait poll.
// ---------------------------------------------------------------------------
__device__ __forceinline__ void poll4(const unsigned long long* __restrict__ slots,
                                      float* __restrict__ dst, int base, unsigned want) {
  u32x4 a, b;
  for (;;) {
    asm volatile("global_load_dwordx4 %0, %2, off sc0 sc1\n\t"
                 "global_load_dwordx4 %1, %3, off sc0 sc1\n\t"
                 "s_waitcnt vmcnt(0)"
                 : "=&v"(a), "=&v"(b)
                 : "v"(slots + base), "v"(slots + base + 2) : "memory");
    if (a.y == want && a.w == want && b.y == want && b.w == want) break;
  }
  dst[base + 0] = __uint_as_float(a.x);
  dst[base + 1] = __uint_as_float(a.z);
  dst[base + 2] = __uint_as_float(b.x);
  dst[base + 3] = __uint_as_float(b.z);
}

__global__ __launch_bounds__(256, 1) void ulstm_persistent_f(
    const float* __restrict__ inputs, const float* __restrict__ Wx,
    const float* __restrict__ bx, const float* __restrict__ Wh,
    const float* __restrict__ bh, const float* __restrict__ Wm,
    const float* __restrict__ bm, float* __restrict__ out,
    unsigned long long* __restrict__ hslot, unsigned long long* __restrict__ vslot)
{
  __shared__ alignas(16) float xbuf[MDIM];
  __shared__ alignas(16) float hbuf[MDIM];
  __shared__ alignas(16) float vbuf[MDIM];

  const int tid  = threadIdx.x;
  const int wg   = blockIdx.x;
  const int wave = tid >> 6;
  const int lane = tid & 63;
  const int j    = wg * 4 + wave;
  const int slotbase = tid * 4;

  const float bxi = bx[j],            bxo = bx[MDIM + j],
              bxz = bx[2 * MDIM + j], bxf = bx[3 * MDIM + j],
              bxu = bx[4 * MDIM + j];
  const float bhi = bh[j],            bho = bh[MDIM + j],
              bhz = bh[2 * MDIM + j], bhf = bh[3 * MDIM + j];
  const float bmj = bm[j];

  float c = 0.f, hlast = 0.f;

  for (int t = 0; t < TSTEPS; ++t) {
    {
      float4 v = ((const float4*)(inputs + (size_t)t * MDIM))[tid];
      ((float4*)xbuf)[tid] = v;
    }
    __syncthreads();

    float xd[5] = {0, 0, 0, 0, 0};
    #pragma unroll
    for (int i = 0; i < 4; ++i) {
      const int kb = i * 256 + lane * 4;
      const float4 xv = *(const float4*)(xbuf + kb);
      #pragma unroll
      for (int g = 0; g < 5; ++g) {
        const float4 w = *(const float4*)(Wx + ((size_t)(g * MDIM + j)) * MDIM + kb);
        xd[g] += w.x * xv.x + w.y * xv.y + w.z * xv.z + w.w * xv.w;
      }
    }
    #pragma unroll
    for (int off = 32; off > 0; off >>= 1)
      #pragma unroll
      for (int g = 0; g < 5; ++g) xd[g] += __shfl_xor(xd[g], off, 64);

    poll4(hslot, hbuf, slotbase, (unsigned)t);
    __syncthreads();

    float hd[4] = {0, 0, 0, 0};
    #pragma unroll
    for (int i = 0; i < 4; ++i) {
      const int kb = i * 256 + lane * 4;
      const float4 hv = *(const float4*)(hbuf + kb);
      #pragma unroll
      for (int g = 0; g < 4; ++g) {
        const float4 w = *(const float4*)(Wh + ((size_t)(g * MDIM + j)) * MDIM + kb);
        hd[g] += w.x * hv.x + w.y * hv.y + w.z * hv.z + w.w * hv.w;
      }
    }
    #pragma unroll
    for (int off = 32; off > 0; off >>= 1)
      #pragma unroll
      for (int g = 0; g < 4; ++g) hd[g] += __shfl_xor(hd[g], off, 64);

    const float ig = sigmoidf_(xd[0] + bxi + hd[0] + bhi);
    const float og = sigmoidf_(xd[1] + bxo + hd[1] + bho);
    const float zg = sigmoidf_(xd[2] + bxz + hd[2] + bhz);
    const float fg = sigmoidf_(xd[3] + bxf + hd[3] + bhf);
    const float vj = zg * tanhf_(c);
    if (lane == 0)
      __hip_atomic_store(vslot + j, pack_slot(vj, (unsigned)(t + 1)),
                         __ATOMIC_RELAXED, __HIP_MEMORY_SCOPE_AGENT);

    poll4(vslot, vbuf, slotbase, (unsigned)(t + 1));
    __syncthreads();

    float md = 0;
    #pragma unroll
    for (int i = 0; i < 4; ++i) {
      const int kb = i * 256 + lane * 4;
      const float4 vv = *(const float4*)(vbuf + kb);
      const float4 w = *(const float4*)(Wm + (size_t)j * MDIM + kb);
      md += w.x * vv.x + w.y * vv.y + w.z * vv.z + w.w * vv.w;
    }
    #pragma unroll
    for (int off = 32; off > 0; off >>= 1) md += __shfl_xor(md, off, 64);

    const float u = tanhf_(xd[4] + bxu + md + bmj);
    c = ig * u + fg * c;
    hlast = og * tanhf_(c);
    if (lane == 0)
      __hip_atomic_store(hslot + j, pack_slot(hlast, (unsigned)(t + 1)),
                         __ATOMIC_RELAXED, __HIP_MEMORY_SCOPE_AGENT);
  }

  if (lane == 0) {
    out[j] = c;
    out[MDIM + j] = hlast;
  }
}

extern "C" void kernel_launch(void* const* d_in, const int* in_sizes, int n_in,
                              void* d_out, int out_size, void* d_ws, size_t ws_size,
                              hipStream_t stream) {
  const float* inputs = (const float*)d_in[0];
  const float* Wx     = (const float*)d_in[1];
  const float* bx     = (const float*)d_in[2];
  const float* Wh     = (const float*)d_in[3];
  const float* bh     = (const float*)d_in[4];
  const float* Wm     = (const float*)d_in[5];
  const float* bm     = (const float*)d_in[6];
  float* out = (float*)d_out;

  unsigned long long* hslot = (unsigned long long*)d_ws;
  unsigned long long* vslot = hslot + MDIM;
  const size_t slot_bytes = 2 * MDIM * sizeof(unsigned long long);
  const size_t xp_bytes   = (size_t)TSTEPS * NGATE5 * sizeof(float);

  hipMemsetAsync(d_ws, 0, slot_bytes, stream);

  if (ws_size >= slot_bytes + xp_bytes) {
    float* xproj = (float*)((char*)d_ws + slot_bytes);
    xproj_gemm<<<dim3(TSTEPS / 64, NGATE5 / 64), 256, 0, stream>>>(
        inputs, Wx, bx, bh, bm, xproj);
    ulstm_persistent_p<<<NWG, NTHR, 0, stream>>>(Wh, Wm, xproj, out, hslot, vslot);
  } else {
    ulstm_persistent_f<<<256, 256, 0, stream>>>(inputs, Wx, bx, Wh, bh, Wm, bm,
                                                out, hslot, vslot);
  }
}